// Round 8
// baseline (6467.493 us; speedup 1.0000x reference)
//
#include <hip/hip_runtime.h>

// ---------------------------------------------------------------------------
// SubtasksRecurrence: T=128 sequential steps, B=256 independent rows.
// R8: o-SPLIT PAIRS. 512 blocks x 128 threads; block (b, half) owns output
//     cols o in [half*128,(half+1)*128) of row b and streams ONLY its half
//     of W_ih/W_hh (0.75 MB/step) -- attacking the measured invariant
//     step_time ~= per-CU stream bytes / 60 GB/s. Pair halves exchange
//     {s,h halves, c/l partials, logits partials} (~1.1 KB/step) through L2
//     with monotonic acquire/release flags (R1-proven pattern, pairwise).
// All arithmetic chains bit-match R6 (passed, absmax 0.0078125): o-split
// does not split K; wave-slot combine orders preserved; sampling replicated.
// ---------------------------------------------------------------------------

#define RNG_PARTITIONABLE 1

#define T_STEPS 128
#define B_ROWS  256
#define TOT     338
#define CONV    4096
#define LDWF    4161   // W_f row stride (CONV + 2S + 1)
#define LDWB    4128   // W_beta row stride (CONV + S)

typedef float v2f __attribute__((ext_vector_type(2)));

// ------------------------------- threefry ----------------------------------
__device__ __forceinline__ void tf2x32(unsigned k0, unsigned k1, unsigned c0, unsigned c1,
                                       unsigned &o0, unsigned &o1) {
  const unsigned ks2 = k0 ^ k1 ^ 0x1BD11BDAu;
  unsigned x0 = c0 + k0;
  unsigned x1 = c1 + k1;
#define TFR(r) { x0 += x1; x1 = (x1 << (r)) | (x1 >> (32 - (r))); x1 ^= x0; }
  TFR(13) TFR(15) TFR(26) TFR(6)
  x0 += k1; x1 += ks2 + 1u;
  TFR(17) TFR(29) TFR(16) TFR(24)
  x0 += ks2; x1 += k0 + 2u;
  TFR(13) TFR(15) TFR(26) TFR(6)
  x0 += k0; x1 += k1 + 3u;
  TFR(17) TFR(29) TFR(16) TFR(24)
  x0 += k1; x1 += ks2 + 4u;
  TFR(13) TFR(15) TFR(26) TFR(6)
  x0 += ks2; x1 += k0 + 5u;
#undef TFR
  o0 = x0; o1 = x1;
}

__device__ __forceinline__ void rng_key(unsigned j, unsigned &k0, unsigned &k1) {
#if RNG_PARTITIONABLE
  tf2x32(0u, 42u, 0u, j, k0, k1);
#else
  unsigned w[2];
  for (int q = 0; q < 2; ++q) {
    unsigned i = 2u*j + (unsigned)q, a, b;
    if (i < 256u) { tf2x32(0u, 42u, i, 256u + i, a, b); w[q] = a; }
    else          { tf2x32(0u, 42u, i - 256u, i, a, b); w[q] = b; }
  }
  k0 = w[0]; k1 = w[1];
#endif
}

__device__ __forceinline__ unsigned rng_bits(unsigned k0, unsigned k1, unsigned idx, unsigned total) {
#if RNG_PARTITIONABLE
  unsigned o0, o1;
  tf2x32(k0, k1, 0u, idx, o0, o1);
  return o0 ^ o1;
#else
  unsigned half = total >> 1, o0, o1;
  if (idx < half) { tf2x32(k0, k1, idx, half + idx, o0, o1); return o0; }
  else            { tf2x32(k0, k1, idx - half, idx, o0, o1); return o1; }
#endif
}

__device__ __forceinline__ float gumbel_from_bits(unsigned bits) {
  float u0 = __uint_as_float(0x3f800000u | (bits >> 9)) - 1.0f;
  float u  = fmaxf(u0, 1.17549435e-38f);
  return -logf(-logf(u));
}

// ------------------------------ small kernels ------------------------------
__global__ __launch_bounds__(256) void rng_k(float* __restrict__ ggum, float* __restrict__ bgum) {
  unsigned tid = blockIdx.x * 256u + threadIdx.x;
  const unsigned NG = T_STEPS * B_ROWS * 16;
  const unsigned NB = T_STEPS * B_ROWS * 2;
  if (tid < NG) {
    unsigned t = tid / (B_ROWS * 16);
    unsigned i = tid % (B_ROWS * 16);
    unsigned k0, k1; rng_key(2u * t, k0, k1);
    ggum[tid] = gumbel_from_bits(rng_bits(k0, k1, i, B_ROWS * 16));
  } else if (tid < NG + NB) {
    unsigned q = tid - NG;
    unsigned t = q / (B_ROWS * 2);
    unsigned i = q % (B_ROWS * 2);
    unsigned k0, k1; rng_key(2u * t + 1u, k0, k1);
    bgum[q] = gumbel_from_bits(rng_bits(k0, k1, i, B_ROWS * 2));
  }
}

// WT4[((k2*2+h2)*3+p)*128+t] = (W_ih[c][2k2], W_hh[c][2k2], W_ih[c][2k2+1], W_hh[c][2k2+1]),
// c = p*256 + h2*128 + t
__global__ __launch_bounds__(256) void prep4_k(const float* __restrict__ W_ih,
                                               const float* __restrict__ W_hh,
                                               float4* __restrict__ WT4) {
  int idx = blockIdx.x * 256 + threadIdx.x;   // 0..98303
  int t = idx & 127;
  int q = idx >> 7;          // k2*6 + h2*3 + p
  int p = q % 3;
  int h2 = (q / 3) & 1;
  int k2 = q / 6;
  int c = p * 256 + h2 * 128 + t;
  WT4[idx] = make_float4(W_ih[(size_t)c * 256 + 2 * k2], W_hh[(size_t)c * 256 + 2 * k2],
                         W_ih[(size_t)c * 256 + 2 * k2 + 1], W_hh[(size_t)c * 256 + 2 * k2 + 1]);
}

__device__ __forceinline__ float waveRed(float v) {
  v += __shfl_down(v, 32, 64);
  v += __shfl_down(v, 16, 64);
  v += __shfl_down(v, 8, 64);
  v += __shfl_down(v, 4, 64);
  v += __shfl_down(v, 2, 64);
  v += __shfl_down(v, 1, 64);
  return v;
}

__global__ __launch_bounds__(256) void bx_k(const float* __restrict__ obs,
                                            const float* __restrict__ W_beta,
                                            const float* __restrict__ b_beta,
                                            float* __restrict__ bxv) {
  int m = blockIdx.x, tid = threadIdx.x;
  const float* row = obs + (size_t)m * CONV;
  float p0 = 0.f, p1 = 0.f;
  for (int i = tid; i < CONV; i += 256) {
    float o = row[i];
    p0 = fmaf(o, W_beta[i], p0);
    p1 = fmaf(o, W_beta[LDWB + i], p1);
  }
  p0 = waveRed(p0); p1 = waveRed(p1);
  __shared__ float sc[2][4];
  int w = tid >> 6;
  if ((tid & 63) == 0) { sc[0][w] = p0; sc[1][w] = p1; }
  __syncthreads();
  if (tid == 0) bxv[(size_t)m * 2 + 0] = sc[0][0] + sc[0][1] + sc[0][2] + sc[0][3] + b_beta[0];
  if (tid == 1) bxv[(size_t)m * 2 + 1] = sc[1][0] + sc[1][1] + sc[1][2] + sc[1][3] + b_beta[1];
}

// ------------------------------- big GEMM ----------------------------------
struct __attribute__((packed, aligned(4))) F4 { float x, y, z, w; };

__global__ __launch_bounds__(256) void gemm1_k(const float* __restrict__ A,
                                               const float* __restrict__ W,
                                               const float* __restrict__ bias,
                                               float* __restrict__ C1) {
  __shared__ __align__(16) float As[32][68];
  __shared__ __align__(16) float Bs[32][68];
  int bid = blockIdx.x;
  int mt = bid & 511, nt = bid >> 9;
  int m0 = mt * 64, n0 = nt * 64;
  int tid = threadIdx.x;
  int tm = tid & 15, tn = tid >> 4;
  int lr = tid >> 2;
  int lc = (tid & 3) * 8;
  v2f acc[4][2];
#pragma unroll
  for (int i = 0; i < 4; ++i) { acc[i][0] = (v2f){0.f, 0.f}; acc[i][1] = (v2f){0.f, 0.f}; }
  for (int k0 = 0; k0 < CONV; k0 += 32) {
    F4 a0 = *(const F4*)(A + (size_t)(m0 + lr) * CONV + k0 + lc);
    F4 a1 = *(const F4*)(A + (size_t)(m0 + lr) * CONV + k0 + lc + 4);
    F4 b0 = *(const F4*)(W + (size_t)(n0 + lr) * LDWF + k0 + lc);
    F4 b1 = *(const F4*)(W + (size_t)(n0 + lr) * LDWF + k0 + lc + 4);
    __syncthreads();
    As[lc + 0][lr] = a0.x; As[lc + 1][lr] = a0.y; As[lc + 2][lr] = a0.z; As[lc + 3][lr] = a0.w;
    As[lc + 4][lr] = a1.x; As[lc + 5][lr] = a1.y; As[lc + 6][lr] = a1.z; As[lc + 7][lr] = a1.w;
    Bs[lc + 0][lr] = b0.x; Bs[lc + 1][lr] = b0.y; Bs[lc + 2][lr] = b0.z; Bs[lc + 3][lr] = b0.w;
    Bs[lc + 4][lr] = b1.x; Bs[lc + 5][lr] = b1.y; Bs[lc + 6][lr] = b1.z; Bs[lc + 7][lr] = b1.w;
    __syncthreads();
#pragma unroll
    for (int kk = 0; kk < 32; ++kk) {
      const float4 av = *(const float4*)&As[kk][tm * 4];
      const float4 bv = *(const float4*)&Bs[kk][tn * 4];
      const v2f bl = (v2f){bv.x, bv.y};
      const v2f bh = (v2f){bv.z, bv.w};
      const float aa[4] = {av.x, av.y, av.z, av.w};
#pragma unroll
      for (int i = 0; i < 4; ++i) {
        v2f ax = (v2f){aa[i], aa[i]};
        acc[i][0] = __builtin_elementwise_fma(ax, bl, acc[i][0]);
        acc[i][1] = __builtin_elementwise_fma(ax, bh, acc[i][1]);
      }
    }
  }
  const int mrow = m0 + tm * 4;
  const int ncol = n0 + tn * 4;
  float4 bv4 = *(const float4*)(bias + ncol);
#pragma unroll
  for (int i = 0; i < 4; ++i) {
    float4 v;
    v.x = acc[i][0].x + bv4.x; v.y = acc[i][0].y + bv4.y;
    v.z = acc[i][1].x + bv4.z; v.w = acc[i][1].y + bv4.w;
    *(float4*)(C1 + (size_t)(mrow + i) * 256 + ncol) = v;
  }
}

// ------------------------------ sequential ---------------------------------
// 512 blocks x 128 threads. half = blockIdx>>8, row b = blockIdx&255.
// Owns o in [half*128, half*128+128); pair exchanges via L2 flags.
__global__ __launch_bounds__(128) void seq_k(
    const float* __restrict__ hx0, const float* __restrict__ task,
    const float* __restrict__ W_f, const float* __restrict__ WT4,
    const float* __restrict__ b_ih, const float* __restrict__ b_hh,
    const float* __restrict__ W_u, const float* __restrict__ b_u,
    const float* __restrict__ W_s, const float* __restrict__ b_s,
    const float* __restrict__ W_pi, const float* __restrict__ b_pi,
    const float* __restrict__ W_beta, const float* __restrict__ C1,
    const float* __restrict__ bxv, const float* __restrict__ ggum,
    const float* __restrict__ bgum, float* __restrict__ pairws,
    float* __restrict__ out) {
  const int half = blockIdx.x >> 8;
  const int b = blockIdx.x & 255;
  const int tid = threadIdx.x;        // 0..127
  const int base = half * 128;
  const int o = base + tid;           // own output index (h-dim)
  const int ph = half ^ 1;
  const float4* __restrict__ wt = (const float4*)WT4;

  // pair buffer: 1024 floats per pair
  float* pbuf = pairws + (size_t)b * 1024;
  float* myE1 = pbuf + half * 272;          // [0:128)=s, [128:256)=h, [256:264)=red4p
  float* pE1  = pbuf + ph * 272;
  float* myE2 = pbuf + 544 + half * 32;     // 32 floats of red16 partials
  float* pE2  = pbuf + 544 + ph * 32;
  unsigned* f2my = (unsigned*)(pbuf + 608) + half * 16;
  unsigned* f2pp = (unsigned*)(pbuf + 608) + ph * 16;
  unsigned* f1my = (unsigned*)(pbuf + 640) + half * 16;
  unsigned* f1pp = (unsigned*)(pbuf + 640) + ph * 16;

  __shared__ float wf_sh[128 * 65];          // 33.3 KB own W_f tail slice
  __shared__ float wpiA_sh[16 * 128];        // W_pi[:, own o] (8 KB)
  __shared__ float wpiB_sh[16 * 32];         // W_pi[:, 256+j] r-part (2 KB)
  __shared__ __align__(16) float4 SH4[128];  // (s[2k], h[2k], s[2k+1], h[2k+1]) full vec
  __shared__ float M_sh[512];
  __shared__ float red4[4][4];
  __shared__ float red16[4][16];
  __shared__ float p_sh[2][16], r_sh[2][32], g_sh[2][32];
  __shared__ float gg_sh[16], bg_sh[2], bx_sh[2];
  __shared__ float wb_sh[2][32], bpi_sh[16];

  // ---- one-time init ----
  for (int i = tid; i < 128 * 65; i += 128) {
    int t2 = i / 65, j = i % 65;
    wf_sh[i] = W_f[(size_t)(base + t2) * LDWF + CONV + j];
  }
  for (int i = tid; i < 16 * 128; i += 128) {
    int o2 = i >> 7, t2 = i & 127;
    wpiA_sh[i] = W_pi[o2 * 288 + base + t2];
  }
  for (int i = tid; i < 16 * 32; i += 128) {
    int o2 = i >> 5, j = i & 31;
    wpiB_sh[i] = W_pi[o2 * 288 + 256 + j];
  }
  for (int i = tid; i < 512; i += 128) M_sh[i] = task[(size_t)b * 512 + i];
  if (tid < 16) p_sh[0][tid] = hx0[b * TOT + tid];
  if (tid < 32) {
    r_sh[0][tid] = hx0[b * TOT + 16 + tid];
    g_sh[0][tid] = hx0[b * TOT + 304 + tid];
    wb_sh[0][tid] = W_beta[CONV + tid];
    wb_sh[1][tid] = W_beta[LDWB + CONV + tid];
  }
  if (tid >= 32 && tid < 48) bpi_sh[tid - 32] = b_pi[tid - 32];
  float bnew = hx0[b * TOT + 336];
  float hold = hx0[b * TOT + 48 + o];

  const float bih_r = b_ih[o], bih_z = b_ih[256 + o], bih_n = b_ih[512 + o];
  const float bhh_r = b_hh[o], bhh_z = b_hh[256 + o], bhh_n = b_hh[512 + o];
  const float wu_s = W_u[o], wu_h = W_u[256 + o];
  const float ws0 = W_s[o], ws1 = W_s[256 + o], ws2 = W_s[512 + o];
  const float bu0 = b_u[0], bs0 = b_s[0], bs1 = b_s[1], bs2 = b_s[2];
  __syncthreads();

  unsigned e1v = 1, e2v = 1;

  // ---- bootstrap: s(0), h(0) own; red4(0) partials; E1 exchange ----
  float sacc;
  {
    const float* wfr = wf_sh + tid * 65;
    sacc = C1[(size_t)b * 256 + o];
#pragma unroll
    for (int j = 0; j < 32; ++j) sacc = fmaf(r_sh[0][j], wfr[j], sacc);
#pragma unroll
    for (int j = 0; j < 32; ++j) sacc = fmaf(g_sh[0][j], wfr[32 + j], sacc);
    sacc = fmaf(bnew, wfr[64], sacc);
  }
  {
    // own SH4 components + E1 payload + red4 partials
    ((float*)&SH4[o >> 1])[(o & 1) * 2]     = sacc;
    ((float*)&SH4[o >> 1])[(o & 1) * 2 + 1] = hold;
    myE1[tid] = sacc;
    myE1[128 + tid] = hold;
    float pc = fmaf(wu_s, sacc, wu_h * hold);
    float q0 = ws0 * hold, q1 = ws1 * hold, q2 = ws2 * hold;
    pc = waveRed(pc); q0 = waveRed(q0); q1 = waveRed(q1); q2 = waveRed(q2);
    int w = tid >> 6;                        // local wave 0..1
    if ((tid & 63) == 0) {
      int slot = half * 2 + w;
      red4[slot][0] = pc; red4[slot][1] = q0; red4[slot][2] = q1; red4[slot][3] = q2;
      myE1[256 + w * 4 + 0] = pc; myE1[256 + w * 4 + 1] = q0;
      myE1[256 + w * 4 + 2] = q1; myE1[256 + w * 4 + 3] = q2;
    }
  }
  __syncthreads();
  if (tid == 0) {
    __hip_atomic_store(f1my, e1v, __ATOMIC_RELEASE, __HIP_MEMORY_SCOPE_AGENT);
    while (__hip_atomic_load(f1pp, __ATOMIC_ACQUIRE, __HIP_MEMORY_SCOPE_AGENT) < e1v)
      __builtin_amdgcn_s_sleep(1);
  }
  __syncthreads();
  {
    float ps = pE1[tid], phh = pE1[128 + tid];
    int pk = ph * 128 + tid;
    ((float*)&SH4[pk >> 1])[(pk & 1) * 2]     = ps;
    ((float*)&SH4[pk >> 1])[(pk & 1) * 2 + 1] = phh;
    if (tid < 8) red4[ph * 2 + (tid >> 2)][tid & 3] = pE1[256 + tid];
  }
  e1v++;
  __syncthreads();

  for (int t = 0; t < T_STEPS; ++t) {
    const int pp = t & 1, np = pp ^ 1;

    // ---- prefetches ----
    int tn2 = (t + 1 < T_STEPS) ? t + 1 : t;
    float c1n = C1[((size_t)tn2 * 256 + b) * 256 + o];
    if (tid < 16) gg_sh[tid] = ggum[((size_t)t * 256 + b) * 16 + tid];
    else if (tid < 18) bg_sh[tid - 16] = bgum[((size_t)t * 256 + b) * 2 + (tid - 16)];
    else if (tid < 20) bx_sh[tid - 18] = bxv[((size_t)t * 256 + b) * 2 + (tid - 18)];

    // ---- stream own weight slice: 3 cols x full K, (gi,gh) packed v2f ----
    v2f a0 = (v2f){0.f, 0.f}, a1 = (v2f){0.f, 0.f}, a2 = (v2f){0.f, 0.f};
#pragma unroll 8
    for (int k2 = 0; k2 < 128; ++k2) {
      const size_t wb2 = (size_t)((k2 * 2 + half) * 3) * 128 + tid;
      float4 w0 = wt[wb2];
      float4 w1 = wt[wb2 + 128];
      float4 w2 = wt[wb2 + 256];
      float4 x = SH4[k2];
      v2f xa = (v2f){x.x, x.y};   // (s[2k2], h[2k2])
      v2f xb = (v2f){x.z, x.w};   // (s[2k2+1], h[2k2+1])
      a0 = __builtin_elementwise_fma(xa, (v2f){w0.x, w0.y}, a0);
      a0 = __builtin_elementwise_fma(xb, (v2f){w0.z, w0.w}, a0);
      a1 = __builtin_elementwise_fma(xa, (v2f){w1.x, w1.y}, a1);
      a1 = __builtin_elementwise_fma(xb, (v2f){w1.z, w1.w}, a1);
      a2 = __builtin_elementwise_fma(xa, (v2f){w2.x, w2.y}, a2);
      a2 = __builtin_elementwise_fma(xb, (v2f){w2.z, w2.w}, a2);
    }

    // ---- c, l (replicated; combine order = global slots 0,1,2,3) ----
    float c, l0, l1, l2;
    {
      float cs = red4[0][0] + red4[1][0] + red4[2][0] + red4[3][0] + bu0;
      c = 1.0f / (1.0f + expf(-cs));
      float x0 = red4[0][1] + red4[1][1] + red4[2][1] + red4[3][1] + bs0;
      float x1 = red4[0][2] + red4[1][2] + red4[2][2] + red4[3][2] + bs1;
      float x2 = red4[0][3] + red4[1][3] + red4[2][3] + red4[3][3] + bs2;
      float m = fmaxf(x0, fmaxf(x1, x2));
      float e0 = expf(x0 - m), e1 = expf(x1 - m), e2 = expf(x2 - m);
      float es = e0 + e1 + e2;
      l0 = e0 / es; l1 = e1 / es; l2 = e2 / es;
    }
    const float omc = 1.0f - c;

    // ---- GRU (own o) ----
    float hg;
    {
      float rr_ = 1.0f / (1.0f + expf(-(a0.x + bih_r + a0.y + bhh_r)));
      float zz  = 1.0f / (1.0f + expf(-(a1.x + bih_z + a1.y + bhh_z)));
      float nn  = tanhf(a2.x + bih_n + rr_ * (a2.y + bhh_n));
      float hnew = (1.0f - zz) * nn + zz * hold;
      hg = c * hnew + omc * hold;
    }

    // ---- p_new, r', p' (replicated smalls) ----
    float pn[16];
#pragma unroll
    for (int i = 0; i < 16; ++i) {
      float pm = (i > 0) ? p_sh[pp][i - 1] : 0.f;
      float pq = (i < 15) ? p_sh[pp][i + 1] : 0.f;
      pn[i] = l0 * pm + l1 * p_sh[pp][i] + l2 * pq;
    }
    float rv = 0.f;
    if (tid < 32) {
      float a = 0.f;
#pragma unroll
      for (int n2 = 0; n2 < 16; ++n2) a = fmaf(pn[n2], M_sh[n2 * 32 + tid], a);
      rv = c * a + omc * r_sh[pp][tid];
      r_sh[np][tid] = rv;
    }
    if (tid < 16) p_sh[np][tid] = c * pn[tid] + omc * p_sh[pp][tid];

    // ---- logits_g partials (own o; r-part only where global o<32 = half0) ----
    {
      float pv[16];
#pragma unroll
      for (int o2 = 0; o2 < 16; ++o2) pv[o2] = hg * wpiA_sh[o2 * 128 + tid];
      if (half == 0 && tid < 32) {
#pragma unroll
        for (int o2 = 0; o2 < 16; ++o2) pv[o2] = fmaf(rv, wpiB_sh[o2 * 32 + tid], pv[o2]);
      }
#pragma unroll
      for (int o2 = 0; o2 < 16; ++o2) pv[o2] = waveRed(pv[o2]);
      int w = tid >> 6;
      if ((tid & 63) == 0) {
        int slot = half * 2 + w;
#pragma unroll
        for (int o2 = 0; o2 < 16; ++o2) { red16[slot][o2] = pv[o2]; myE2[w * 16 + o2] = pv[o2]; }
      }
    }
    __syncthreads();                                  // payload + stream reads done
    if (tid == 0) {
      __hip_atomic_store(f2my, e2v, __ATOMIC_RELEASE, __HIP_MEMORY_SCOPE_AGENT);
      while (__hip_atomic_load(f2pp, __ATOMIC_ACQUIRE, __HIP_MEMORY_SCOPE_AGENT) < e2v)
        __builtin_amdgcn_s_sleep(1);
    }
    __syncthreads();
    if (tid < 32) red16[ph * 2 + (tid >> 4)][tid & 15] = pE2[tid];
    e2v++;
    __syncthreads();

    // ---- g-sample (replicated) ----
    int gidx = 0;
    float lpg;
    {
      float lg[16];
#pragma unroll
      for (int n2 = 0; n2 < 16; ++n2)
        lg[n2] = red16[0][n2] + red16[1][n2] + red16[2][n2] + red16[3][n2] + bpi_sh[n2];
      float best = -3.402823466e+38f;
      for (int n2 = 0; n2 < 16; ++n2) {
        float v = lg[n2] + gg_sh[n2];
        if (v > best) { best = v; gidx = n2; }
      }
      float mx = lg[0];
      for (int n2 = 1; n2 < 16; ++n2) mx = fmaxf(mx, lg[n2]);
      float se = 0.f;
      for (int n2 = 0; n2 < 16; ++n2) se += expf(lg[n2] - mx);
      lpg = lg[gidx] - mx - logf(se);
    }
    if (tid < 32) g_sh[np][tid] = c * M_sh[gidx * 32 + tid] + omc * g_sh[pp][tid];
    __syncthreads();

    // ---- b-sample (replicated); next s (own); state publish; outputs ----
    float lpt;
    {
      float lb0 = bx_sh[0], lb1 = bx_sh[1];
      for (int s2 = 0; s2 < 32; ++s2) {
        float gv = g_sh[np][s2];
        lb0 = fmaf(gv, wb_sh[0][s2], lb0);
        lb1 = fmaf(gv, wb_sh[1][s2], lb1);
      }
      int bidx = ((lb1 + bg_sh[1]) > (lb0 + bg_sh[0])) ? 1 : 0;
      float mb = fmaxf(lb0, lb1);
      float seb = expf(lb0 - mb) + expf(lb1 - mb);
      bnew = (float)bidx;
      lpt = lpg + ((bidx ? lb1 : lb0) - mb - logf(seb));
    }
    {
      const float* wfr = wf_sh + tid * 65;
      sacc = c1n;
#pragma unroll
      for (int j = 0; j < 32; ++j) sacc = fmaf(r_sh[np][j], wfr[j], sacc);
#pragma unroll
      for (int j = 0; j < 32; ++j) sacc = fmaf(g_sh[np][j], wfr[32 + j], sacc);
      sacc = fmaf(bnew, wfr[64], sacc);
    }
    hold = hg;
    // own SH4 update + E1 payload + red4(t+1) partials
    ((float*)&SH4[o >> 1])[(o & 1) * 2]     = sacc;
    ((float*)&SH4[o >> 1])[(o & 1) * 2 + 1] = hold;
    if (t < T_STEPS - 1) {
      myE1[tid] = sacc;
      myE1[128 + tid] = hold;
    }
    {
      float pc = fmaf(wu_s, sacc, wu_h * hold);
      float q0 = ws0 * hold, q1 = ws1 * hold, q2 = ws2 * hold;
      pc = waveRed(pc); q0 = waveRed(q0); q1 = waveRed(q1); q2 = waveRed(q2);
      int w = tid >> 6;
      if ((tid & 63) == 0) {
        int slot = half * 2 + w;
        red4[slot][0] = pc; red4[slot][1] = q0; red4[slot][2] = q1; red4[slot][3] = q2;
        if (t < T_STEPS - 1) {
          myE1[256 + w * 4 + 0] = pc; myE1[256 + w * 4 + 1] = q0;
          myE1[256 + w * 4 + 2] = q1; myE1[256 + w * 4 + 3] = q2;
        }
      }
    }
    // outputs: [p16, r32, h256, g32, b1, lp1]
    {
      size_t obase = ((size_t)t * 256 + b) * TOT;
      out[obase + 48 + o] = hg;
      if (half == 0) {
        if (tid < 16) out[obase + tid] = p_sh[np][tid];
        else if (tid < 48) out[obase + tid] = r_sh[np][tid - 16];
      } else {
        if (tid < 32) out[obase + 304 + tid] = g_sh[np][tid];
        else if (tid == 32) out[obase + 336] = bnew;
        else if (tid == 33) out[obase + 337] = lpt;
      }
    }
    if (t < T_STEPS - 1) {
      __syncthreads();
      if (tid == 0) {
        __hip_atomic_store(f1my, e1v, __ATOMIC_RELEASE, __HIP_MEMORY_SCOPE_AGENT);
        while (__hip_atomic_load(f1pp, __ATOMIC_ACQUIRE, __HIP_MEMORY_SCOPE_AGENT) < e1v)
          __builtin_amdgcn_s_sleep(1);
      }
      __syncthreads();
      {
        float ps = pE1[tid], phh = pE1[128 + tid];
        int pk = ph * 128 + tid;
        ((float*)&SH4[pk >> 1])[(pk & 1) * 2]     = ps;
        ((float*)&SH4[pk >> 1])[(pk & 1) * 2 + 1] = phh;
        if (tid < 8) red4[ph * 2 + (tid >> 2)][tid & 3] = pE1[256 + tid];
      }
      e1v++;
      __syncthreads();
    }
  }
}

// ------------------------------ host launch --------------------------------
extern "C" void kernel_launch(void* const* d_in, const int* in_sizes, int n_in,
                              void* d_out, int out_size, void* d_ws, size_t ws_size,
                              hipStream_t stream) {
  const float* obs    = (const float*)d_in[0];
  const float* task   = (const float*)d_in[1];
  const float* hx0    = (const float*)d_in[2];
  const float* W_ih   = (const float*)d_in[3];
  const float* W_hh   = (const float*)d_in[4];
  const float* b_ih   = (const float*)d_in[5];
  const float* b_hh   = (const float*)d_in[6];
  const float* W_f    = (const float*)d_in[7];
  const float* b_f    = (const float*)d_in[8];
  const float* W_u    = (const float*)d_in[9];
  const float* b_u    = (const float*)d_in[10];
  const float* W_s    = (const float*)d_in[11];
  const float* b_s    = (const float*)d_in[12];
  const float* W_pi   = (const float*)d_in[13];
  const float* b_pi   = (const float*)d_in[14];
  const float* W_beta = (const float*)d_in[15];
  const float* b_beta = (const float*)d_in[16];

  char* ws = (char*)d_ws;
  size_t off = 0;
  auto take = [&](size_t bytes) {
    size_t r = off;
    off += (bytes + 255) & ~(size_t)255;
    return r;
  };
  size_t off_WT4  = take((size_t)98304 * 16);
  size_t off_ggum = take((size_t)T_STEPS * B_ROWS * 16 * 4);
  size_t off_bgum = take((size_t)T_STEPS * B_ROWS * 2 * 4);
  size_t off_bx   = take((size_t)T_STEPS * B_ROWS * 2 * 4);
  size_t off_pair = take((size_t)256 * 1024 * 4);
  size_t off_C1   = take((size_t)T_STEPS * B_ROWS * 256 * 4);
  if (off > ws_size) return;

  float* WT4    = (float*)(ws + off_WT4);
  float* ggum   = (float*)(ws + off_ggum);
  float* bgum   = (float*)(ws + off_bgum);
  float* bxv    = (float*)(ws + off_bx);
  float* pairws = (float*)(ws + off_pair);
  float* C1     = (float*)(ws + off_C1);

  hipMemsetAsync(ws + off_pair, 0, (size_t)256 * 1024 * 4, stream);
  hipLaunchKernelGGL(prep4_k, dim3(384), dim3(256), 0, stream, W_ih, W_hh, (float4*)WT4);
  hipLaunchKernelGGL(rng_k, dim3(2304), dim3(256), 0, stream, ggum, bgum);
  hipLaunchKernelGGL(gemm1_k, dim3(2048), dim3(256), 0, stream, obs, W_f, b_f, C1);
  hipLaunchKernelGGL(bx_k, dim3(32768), dim3(256), 0, stream, obs, W_beta, b_beta, bxv);
  hipLaunchKernelGGL(seq_k, dim3(512), dim3(128), 0, stream,
                     hx0, task, W_f, WT4, b_ih, b_hh, W_u, b_u, W_s, b_s, W_pi, b_pi,
                     W_beta, C1, bxv, ggum, bgum, pairws, (float*)d_out);
}

// Round 9
// 3997.968 us; speedup vs baseline: 1.6177x; 1.6177x over previous
//
#include <hip/hip_runtime.h>

// ---------------------------------------------------------------------------
// SubtasksRecurrence: T=128 sequential steps, B=256 independent rows.
// R9: R6 structure (128 blocks x 256 thr, 2 rows/block) with:
//     (1) WT4 duplicated x2 (3 MB, fits per-XCD L2); copy=(blockIdx>>3)&1
//         halves same-cacheline sharers per XCD (multicast-serialization test).
//     (2) 2 barriers/step (was 5): SH4 parity-double-buffered (stream reads
//         [pp], h'/s' write [np]); g-gating replicated inline in phase C.
// All accumulation chains use R6's exact expressions/orders (passed, 0.0078).
// Cross-block sync: NONE (R8 measured ~10us/round -> forbidden).
// ---------------------------------------------------------------------------

#define RNG_PARTITIONABLE 1

#define T_STEPS 128
#define B_ROWS  256
#define TOT     338
#define CONV    4096
#define LDWF    4161   // W_f row stride (CONV + 2S + 1)
#define LDWB    4128   // W_beta row stride (CONV + S)

typedef float v2f __attribute__((ext_vector_type(2)));

// ------------------------------- threefry ----------------------------------
__device__ __forceinline__ void tf2x32(unsigned k0, unsigned k1, unsigned c0, unsigned c1,
                                       unsigned &o0, unsigned &o1) {
  const unsigned ks2 = k0 ^ k1 ^ 0x1BD11BDAu;
  unsigned x0 = c0 + k0;
  unsigned x1 = c1 + k1;
#define TFR(r) { x0 += x1; x1 = (x1 << (r)) | (x1 >> (32 - (r))); x1 ^= x0; }
  TFR(13) TFR(15) TFR(26) TFR(6)
  x0 += k1; x1 += ks2 + 1u;
  TFR(17) TFR(29) TFR(16) TFR(24)
  x0 += ks2; x1 += k0 + 2u;
  TFR(13) TFR(15) TFR(26) TFR(6)
  x0 += k0; x1 += k1 + 3u;
  TFR(17) TFR(29) TFR(16) TFR(24)
  x0 += k1; x1 += ks2 + 4u;
  TFR(13) TFR(15) TFR(26) TFR(6)
  x0 += ks2; x1 += k0 + 5u;
#undef TFR
  o0 = x0; o1 = x1;
}

__device__ __forceinline__ void rng_key(unsigned j, unsigned &k0, unsigned &k1) {
#if RNG_PARTITIONABLE
  tf2x32(0u, 42u, 0u, j, k0, k1);
#else
  unsigned w[2];
  for (int q = 0; q < 2; ++q) {
    unsigned i = 2u*j + (unsigned)q, a, b;
    if (i < 256u) { tf2x32(0u, 42u, i, 256u + i, a, b); w[q] = a; }
    else          { tf2x32(0u, 42u, i - 256u, i, a, b); w[q] = b; }
  }
  k0 = w[0]; k1 = w[1];
#endif
}

__device__ __forceinline__ unsigned rng_bits(unsigned k0, unsigned k1, unsigned idx, unsigned total) {
#if RNG_PARTITIONABLE
  unsigned o0, o1;
  tf2x32(k0, k1, 0u, idx, o0, o1);
  return o0 ^ o1;
#else
  unsigned half = total >> 1, o0, o1;
  if (idx < half) { tf2x32(k0, k1, idx, half + idx, o0, o1); return o0; }
  else            { tf2x32(k0, k1, idx - half, idx, o0, o1); return o1; }
#endif
}

__device__ __forceinline__ float gumbel_from_bits(unsigned bits) {
  float u0 = __uint_as_float(0x3f800000u | (bits >> 9)) - 1.0f;
  float u  = fmaxf(u0, 1.17549435e-38f);
  return -logf(-logf(u));
}

// ------------------------------ small kernels ------------------------------
__global__ __launch_bounds__(256) void rng_k(float* __restrict__ ggum, float* __restrict__ bgum) {
  unsigned tid = blockIdx.x * 256u + threadIdx.x;
  const unsigned NG = T_STEPS * B_ROWS * 16;
  const unsigned NB = T_STEPS * B_ROWS * 2;
  if (tid < NG) {
    unsigned t = tid / (B_ROWS * 16);
    unsigned i = tid % (B_ROWS * 16);
    unsigned k0, k1; rng_key(2u * t, k0, k1);
    ggum[tid] = gumbel_from_bits(rng_bits(k0, k1, i, B_ROWS * 16));
  } else if (tid < NG + NB) {
    unsigned q = tid - NG;
    unsigned t = q / (B_ROWS * 2);
    unsigned i = q % (B_ROWS * 2);
    unsigned k0, k1; rng_key(2u * t + 1u, k0, k1);
    bgum[q] = gumbel_from_bits(rng_bits(k0, k1, i, B_ROWS * 2));
  }
}

// WT4[copy][k2*768 + col] = (W_ih[col][2k2], W_hh[col][2k2], W_ih[col][2k2+1], W_hh[col][2k2+1])
__global__ __launch_bounds__(768) void prep4_k(const float* __restrict__ W_ih,
                                               const float* __restrict__ W_hh,
                                               float4* __restrict__ WT4) {
  int k2 = blockIdx.x & 127;
  int copy = blockIdx.x >> 7;
  int col = threadIdx.x;     // 0..767
  float a0 = W_ih[(size_t)col * 256 + 2 * k2];
  float a1 = W_ih[(size_t)col * 256 + 2 * k2 + 1];
  float b0 = W_hh[(size_t)col * 256 + 2 * k2];
  float b1 = W_hh[(size_t)col * 256 + 2 * k2 + 1];
  WT4[(size_t)copy * 98304 + (size_t)k2 * 768 + col] = make_float4(a0, b0, a1, b1);
}

__device__ __forceinline__ float waveRed(float v) {
  v += __shfl_down(v, 32, 64);
  v += __shfl_down(v, 16, 64);
  v += __shfl_down(v, 8, 64);
  v += __shfl_down(v, 4, 64);
  v += __shfl_down(v, 2, 64);
  v += __shfl_down(v, 1, 64);
  return v;
}

__global__ __launch_bounds__(256) void bx_k(const float* __restrict__ obs,
                                            const float* __restrict__ W_beta,
                                            const float* __restrict__ b_beta,
                                            float* __restrict__ bxv) {
  int m = blockIdx.x, tid = threadIdx.x;
  const float* row = obs + (size_t)m * CONV;
  float p0 = 0.f, p1 = 0.f;
  for (int i = tid; i < CONV; i += 256) {
    float o = row[i];
    p0 = fmaf(o, W_beta[i], p0);
    p1 = fmaf(o, W_beta[LDWB + i], p1);
  }
  p0 = waveRed(p0); p1 = waveRed(p1);
  __shared__ float sc[2][4];
  int w = tid >> 6;
  if ((tid & 63) == 0) { sc[0][w] = p0; sc[1][w] = p1; }
  __syncthreads();
  if (tid == 0) bxv[(size_t)m * 2 + 0] = sc[0][0] + sc[0][1] + sc[0][2] + sc[0][3] + b_beta[0];
  if (tid == 1) bxv[(size_t)m * 2 + 1] = sc[1][0] + sc[1][1] + sc[1][2] + sc[1][3] + b_beta[1];
}

// ------------------------------- big GEMM ----------------------------------
struct __attribute__((packed, aligned(4))) F4 { float x, y, z, w; };

__global__ __launch_bounds__(256) void gemm1_k(const float* __restrict__ A,
                                               const float* __restrict__ W,
                                               const float* __restrict__ bias,
                                               float* __restrict__ C1) {
  __shared__ __align__(16) float As[32][68];
  __shared__ __align__(16) float Bs[32][68];
  int bid = blockIdx.x;
  int mt = bid & 511, nt = bid >> 9;
  int m0 = mt * 64, n0 = nt * 64;
  int tid = threadIdx.x;
  int tm = tid & 15, tn = tid >> 4;
  int lr = tid >> 2;
  int lc = (tid & 3) * 8;
  v2f acc[4][2];
#pragma unroll
  for (int i = 0; i < 4; ++i) { acc[i][0] = (v2f){0.f, 0.f}; acc[i][1] = (v2f){0.f, 0.f}; }
  for (int k0 = 0; k0 < CONV; k0 += 32) {
    F4 a0 = *(const F4*)(A + (size_t)(m0 + lr) * CONV + k0 + lc);
    F4 a1 = *(const F4*)(A + (size_t)(m0 + lr) * CONV + k0 + lc + 4);
    F4 b0 = *(const F4*)(W + (size_t)(n0 + lr) * LDWF + k0 + lc);
    F4 b1 = *(const F4*)(W + (size_t)(n0 + lr) * LDWF + k0 + lc + 4);
    __syncthreads();
    As[lc + 0][lr] = a0.x; As[lc + 1][lr] = a0.y; As[lc + 2][lr] = a0.z; As[lc + 3][lr] = a0.w;
    As[lc + 4][lr] = a1.x; As[lc + 5][lr] = a1.y; As[lc + 6][lr] = a1.z; As[lc + 7][lr] = a1.w;
    Bs[lc + 0][lr] = b0.x; Bs[lc + 1][lr] = b0.y; Bs[lc + 2][lr] = b0.z; Bs[lc + 3][lr] = b0.w;
    Bs[lc + 4][lr] = b1.x; Bs[lc + 5][lr] = b1.y; Bs[lc + 6][lr] = b1.z; Bs[lc + 7][lr] = b1.w;
    __syncthreads();
#pragma unroll
    for (int kk = 0; kk < 32; ++kk) {
      const float4 av = *(const float4*)&As[kk][tm * 4];
      const float4 bv = *(const float4*)&Bs[kk][tn * 4];
      const v2f bl = (v2f){bv.x, bv.y};
      const v2f bh = (v2f){bv.z, bv.w};
      const float aa[4] = {av.x, av.y, av.z, av.w};
#pragma unroll
      for (int i = 0; i < 4; ++i) {
        v2f ax = (v2f){aa[i], aa[i]};
        acc[i][0] = __builtin_elementwise_fma(ax, bl, acc[i][0]);
        acc[i][1] = __builtin_elementwise_fma(ax, bh, acc[i][1]);
      }
    }
  }
  const int mrow = m0 + tm * 4;
  const int ncol = n0 + tn * 4;
  float4 bv4 = *(const float4*)(bias + ncol);
#pragma unroll
  for (int i = 0; i < 4; ++i) {
    float4 v;
    v.x = acc[i][0].x + bv4.x; v.y = acc[i][0].y + bv4.y;
    v.z = acc[i][1].x + bv4.z; v.w = acc[i][1].y + bv4.w;
    *(float4*)(C1 + (size_t)(mrow + i) * 256 + ncol) = v;
  }
}

// ------------------------------ sequential ---------------------------------
// 128 blocks x 256 threads (4 waves); block owns batch rows {2b, 2b+1}.
__global__ __launch_bounds__(256, 1) void seq_k(
    const float* __restrict__ hx0, const float* __restrict__ task,
    const float* __restrict__ W_f, const float* __restrict__ WT4,
    const float* __restrict__ b_ih, const float* __restrict__ b_hh,
    const float* __restrict__ W_u, const float* __restrict__ b_u,
    const float* __restrict__ W_s, const float* __restrict__ b_s,
    const float* __restrict__ W_pi, const float* __restrict__ b_pi,
    const float* __restrict__ W_beta, const float* __restrict__ C1,
    const float* __restrict__ bxv, const float* __restrict__ ggum,
    const float* __restrict__ bgum, float* __restrict__ out) {
  const int b2 = blockIdx.x;          // 0..127
  const int tid = threadIdx.x;        // 0..255
  const int o = tid;
  const int brow0 = 2 * b2, brow1 = 2 * b2 + 1;
  // copy selection: spreads same-line sharers across 2 byte-identical copies
  const float4* __restrict__ wt = (const float4*)WT4 + (size_t)((b2 >> 3) & 1) * 98304;

  __shared__ float wf_sh[65 * 256];              // 66.6 KB
  __shared__ float wpi_sh[288 * 16];             // 18.4 KB
  __shared__ __align__(16) float4 SH4[2][2][128];// [parity][row][k2]=(s[2k],h[2k],s[2k+1],h[2k+1])
  __shared__ float M_sh[2][512];
  __shared__ float red4[2][4][4];
  __shared__ float red16[2][4][16];
  __shared__ float p_sh[2][2][16];               // [row][parity][n]
  __shared__ float r_sh[2][2][32];
  __shared__ float g_sh[2][2][32];
  __shared__ float gg_sh[2][16], bg_sh[2][2], bx_sh[2][2];
  __shared__ float wb_sh[2][32], bpi_sh[16];

  // ---- one-time init ----
  for (int i = tid; i < 65 * 256; i += 256) {
    int oo = i / 65, j = i % 65;
    wf_sh[i] = W_f[(size_t)oo * LDWF + CONV + j];
  }
  for (int i = tid; i < 288 * 16; i += 256) wpi_sh[i] = W_pi[i];
  float hold0 = hx0[brow0 * TOT + 48 + o];
  float hold1 = hx0[brow1 * TOT + 48 + o];
  if (tid < 16) {
    p_sh[0][0][tid] = hx0[brow0 * TOT + tid];
    p_sh[1][0][tid] = hx0[brow1 * TOT + tid];
  }
  if (tid < 32) {
    r_sh[0][0][tid] = hx0[brow0 * TOT + 16 + tid];
    r_sh[1][0][tid] = hx0[brow1 * TOT + 16 + tid];
    g_sh[0][0][tid] = hx0[brow0 * TOT + 304 + tid];
    g_sh[1][0][tid] = hx0[brow1 * TOT + 304 + tid];
    wb_sh[0][tid] = W_beta[CONV + tid];
    wb_sh[1][tid] = W_beta[LDWB + CONV + tid];
  }
  if (tid >= 32 && tid < 48) bpi_sh[tid - 32] = b_pi[tid - 32];
  M_sh[0][tid] = task[(size_t)brow0 * 512 + tid];
  M_sh[0][256 + tid] = task[(size_t)brow0 * 512 + 256 + tid];
  M_sh[1][tid] = task[(size_t)brow1 * 512 + tid];
  M_sh[1][256 + tid] = task[(size_t)brow1 * 512 + 256 + tid];
  float bnew0 = hx0[brow0 * TOT + 336];
  float bnew1 = hx0[brow1 * TOT + 336];

  const float bih_r = b_ih[o], bih_z = b_ih[256 + o], bih_n = b_ih[512 + o];
  const float bhh_r = b_hh[o], bhh_z = b_hh[256 + o], bhh_n = b_hh[512 + o];
  const float wu_s = W_u[o], wu_h = W_u[256 + o];
  const float ws0 = W_s[o], ws1 = W_s[256 + o], ws2 = W_s[512 + o];
  const float bu0 = b_u[0], bs0 = b_s[0], bs1 = b_s[1], bs2 = b_s[2];
  __syncthreads();

  // ---- bootstrap: s(0), SH4[0] fill, red4(0) partials ----
  float sacc0, sacc1;
  {
    const float* wfr = wf_sh + o * 65;
    sacc0 = C1[(size_t)brow0 * 256 + o];
    sacc1 = C1[(size_t)brow1 * 256 + o];
#pragma unroll
    for (int j = 0; j < 32; ++j) sacc0 = fmaf(r_sh[0][0][j], wfr[j], sacc0);
#pragma unroll
    for (int j = 0; j < 32; ++j) sacc0 = fmaf(g_sh[0][0][j], wfr[32 + j], sacc0);
    sacc0 = fmaf(bnew0, wfr[64], sacc0);
#pragma unroll
    for (int j = 0; j < 32; ++j) sacc1 = fmaf(r_sh[1][0][j], wfr[j], sacc1);
#pragma unroll
    for (int j = 0; j < 32; ++j) sacc1 = fmaf(g_sh[1][0][j], wfr[32 + j], sacc1);
    sacc1 = fmaf(bnew1, wfr[64], sacc1);
    ((float*)&SH4[0][0][o >> 1])[(o & 1) * 2]     = sacc0;
    ((float*)&SH4[0][0][o >> 1])[(o & 1) * 2 + 1] = hold0;
    ((float*)&SH4[0][1][o >> 1])[(o & 1) * 2]     = sacc1;
    ((float*)&SH4[0][1][o >> 1])[(o & 1) * 2 + 1] = hold1;
  }
  {
    float pc0 = fmaf(wu_s, sacc0, wu_h * hold0);
    float q00 = ws0 * hold0, q01 = ws1 * hold0, q02 = ws2 * hold0;
    float pc1 = fmaf(wu_s, sacc1, wu_h * hold1);
    float q10 = ws0 * hold1, q11 = ws1 * hold1, q12 = ws2 * hold1;
    pc0 = waveRed(pc0); q00 = waveRed(q00); q01 = waveRed(q01); q02 = waveRed(q02);
    pc1 = waveRed(pc1); q10 = waveRed(q10); q11 = waveRed(q11); q12 = waveRed(q12);
    int w4 = tid >> 6;
    if ((tid & 63) == 0) {
      red4[0][w4][0] = pc0; red4[0][w4][1] = q00; red4[0][w4][2] = q01; red4[0][w4][3] = q02;
      red4[1][w4][0] = pc1; red4[1][w4][1] = q10; red4[1][w4][2] = q11; red4[1][w4][3] = q12;
    }
  }
  __syncthreads();

  for (int t = 0; t < T_STEPS; ++t) {
    const int pp = t & 1, np = pp ^ 1;

    // ================= Phase AB =================
    // prefetches
    int tn2 = (t + 1 < T_STEPS) ? t + 1 : t;
    float c1n0 = C1[((size_t)tn2 * 256 + brow0) * 256 + o];
    float c1n1 = C1[((size_t)tn2 * 256 + brow1) * 256 + o];
    if (tid < 32) {
      int rr = tid >> 4, j = tid & 15;
      gg_sh[rr][j] = ggum[((size_t)t * 256 + brow0 + rr) * 16 + j];
    } else if (tid < 36) {
      int q = tid - 32;
      bg_sh[q >> 1][q & 1] = bgum[((size_t)t * 256 + brow0 + (q >> 1)) * 2 + (q & 1)];
    } else if (tid < 40) {
      int q = tid - 36;
      bx_sh[q >> 1][q & 1] = bxv[((size_t)t * 256 + brow0 + (q >> 1)) * 2 + (q & 1)];
    }

    // packed weight stream (reads SH4[pp], verbatim R6 chains)
    v2f ar0 = (v2f){0.f, 0.f}, az0 = (v2f){0.f, 0.f}, an0 = (v2f){0.f, 0.f};
    v2f ar1 = (v2f){0.f, 0.f}, az1 = (v2f){0.f, 0.f}, an1 = (v2f){0.f, 0.f};
#pragma unroll 4
    for (int k2 = 0; k2 < 128; ++k2) {
      float4 wr = wt[(size_t)(k2 * 3 + 0) * 256 + o];
      float4 wz = wt[(size_t)(k2 * 3 + 1) * 256 + o];
      float4 wn = wt[(size_t)(k2 * 3 + 2) * 256 + o];
      float4 x0 = SH4[pp][0][k2];
      float4 x1 = SH4[pp][1][k2];
      v2f xa0 = (v2f){x0.x, x0.y}, xb0 = (v2f){x0.z, x0.w};
      v2f xa1 = (v2f){x1.x, x1.y}, xb1 = (v2f){x1.z, x1.w};
      ar0 = __builtin_elementwise_fma(xa0, (v2f){wr.x, wr.y}, ar0);
      ar0 = __builtin_elementwise_fma(xb0, (v2f){wr.z, wr.w}, ar0);
      az0 = __builtin_elementwise_fma(xa0, (v2f){wz.x, wz.y}, az0);
      az0 = __builtin_elementwise_fma(xb0, (v2f){wz.z, wz.w}, az0);
      an0 = __builtin_elementwise_fma(xa0, (v2f){wn.x, wn.y}, an0);
      an0 = __builtin_elementwise_fma(xb0, (v2f){wn.z, wn.w}, an0);
      ar1 = __builtin_elementwise_fma(xa1, (v2f){wr.x, wr.y}, ar1);
      ar1 = __builtin_elementwise_fma(xb1, (v2f){wr.z, wr.w}, ar1);
      az1 = __builtin_elementwise_fma(xa1, (v2f){wz.x, wz.y}, az1);
      az1 = __builtin_elementwise_fma(xb1, (v2f){wz.z, wz.w}, az1);
      an1 = __builtin_elementwise_fma(xa1, (v2f){wn.x, wn.y}, an1);
      an1 = __builtin_elementwise_fma(xb1, (v2f){wn.z, wn.w}, an1);
    }

    // redundant c,l per row (red4 from previous phase C, synced)
    float c0, c1, l00, l01, l02, l10, l11, l12;
    {
      float cs0 = red4[0][0][0] + red4[0][1][0] + red4[0][2][0] + red4[0][3][0] + bu0;
      c0 = 1.0f / (1.0f + expf(-cs0));
      float x0 = red4[0][0][1] + red4[0][1][1] + red4[0][2][1] + red4[0][3][1] + bs0;
      float x1 = red4[0][0][2] + red4[0][1][2] + red4[0][2][2] + red4[0][3][2] + bs1;
      float x2 = red4[0][0][3] + red4[0][1][3] + red4[0][2][3] + red4[0][3][3] + bs2;
      float m = fmaxf(x0, fmaxf(x1, x2));
      float e0 = expf(x0 - m), e1 = expf(x1 - m), e2 = expf(x2 - m);
      float es = e0 + e1 + e2;
      l00 = e0 / es; l01 = e1 / es; l02 = e2 / es;
      float cs1 = red4[1][0][0] + red4[1][1][0] + red4[1][2][0] + red4[1][3][0] + bu0;
      c1 = 1.0f / (1.0f + expf(-cs1));
      float y0 = red4[1][0][1] + red4[1][1][1] + red4[1][2][1] + red4[1][3][1] + bs0;
      float y1 = red4[1][0][2] + red4[1][1][2] + red4[1][2][2] + red4[1][3][2] + bs1;
      float y2 = red4[1][0][3] + red4[1][1][3] + red4[1][2][3] + red4[1][3][3] + bs2;
      float mm = fmaxf(y0, fmaxf(y1, y2));
      float f0 = expf(y0 - mm), f1 = expf(y1 - mm), f2 = expf(y2 - mm);
      float fs = f0 + f1 + f2;
      l10 = f0 / fs; l11 = f1 / fs; l12 = f2 / fs;
    }
    const float omc0 = 1.0f - c0, omc1 = 1.0f - c1;

    // pn; GRU -> h' into SH4[np]
    float pn0[16], pn1[16];
#pragma unroll
    for (int i = 0; i < 16; ++i) {
      float pm0 = (i > 0) ? p_sh[0][pp][i - 1] : 0.f;
      float pq0 = (i < 15) ? p_sh[0][pp][i + 1] : 0.f;
      pn0[i] = l00 * pm0 + l01 * p_sh[0][pp][i] + l02 * pq0;
      float pm1 = (i > 0) ? p_sh[1][pp][i - 1] : 0.f;
      float pq1 = (i < 15) ? p_sh[1][pp][i + 1] : 0.f;
      pn1[i] = l10 * pm1 + l11 * p_sh[1][pp][i] + l12 * pq1;
    }
    float hg0, hg1;
    {
      float rr_ = 1.0f / (1.0f + expf(-(ar0.x + bih_r + ar0.y + bhh_r)));
      float zz = 1.0f / (1.0f + expf(-(az0.x + bih_z + az0.y + bhh_z)));
      float nn = tanhf(an0.x + bih_n + rr_ * (an0.y + bhh_n));
      float hnew = (1.0f - zz) * nn + zz * hold0;
      hg0 = c0 * hnew + omc0 * hold0;
      ((float*)&SH4[np][0][o >> 1])[(o & 1) * 2 + 1] = hg0;
      float rr1 = 1.0f / (1.0f + expf(-(ar1.x + bih_r + ar1.y + bhh_r)));
      float zz1 = 1.0f / (1.0f + expf(-(az1.x + bih_z + az1.y + bhh_z)));
      float nn1 = tanhf(an1.x + bih_n + rr1 * (an1.y + bhh_n));
      float hnew1 = (1.0f - zz1) * nn1 + zz1 * hold1;
      hg1 = c1 * hnew1 + omc1 * hold1;
      ((float*)&SH4[np][1][o >> 1])[(o & 1) * 2 + 1] = hg1;
    }
    float rv0 = 0.f, rv1 = 0.f;
    if (tid < 32) {
      float a0 = 0.f, a1 = 0.f;
#pragma unroll
      for (int n2 = 0; n2 < 16; ++n2) a0 = fmaf(pn0[n2], M_sh[0][n2 * 32 + o], a0);
#pragma unroll
      for (int n2 = 0; n2 < 16; ++n2) a1 = fmaf(pn1[n2], M_sh[1][n2 * 32 + o], a1);
      rv0 = c0 * a0 + omc0 * r_sh[0][pp][o];
      rv1 = c1 * a1 + omc1 * r_sh[1][pp][o];
      r_sh[0][np][o] = rv0;
      r_sh[1][np][o] = rv1;
    }
    if (tid < 16) {
      p_sh[0][np][o] = c0 * pn0[o] + omc0 * p_sh[0][pp][o];
      p_sh[1][np][o] = c1 * pn1[o] + omc1 * p_sh[1][pp][o];
    }
    // logits partials (verbatim R6)
    {
      float pv0[16], pv1[16];
#pragma unroll
      for (int o2 = 0; o2 < 16; ++o2) {
        pv0[o2] = hg0 * wpi_sh[o2 * 288 + o];
        pv1[o2] = hg1 * wpi_sh[o2 * 288 + o];
      }
      if (tid < 32) {
#pragma unroll
        for (int o2 = 0; o2 < 16; ++o2) {
          pv0[o2] = fmaf(rv0, wpi_sh[o2 * 288 + 256 + o], pv0[o2]);
          pv1[o2] = fmaf(rv1, wpi_sh[o2 * 288 + 256 + o], pv1[o2]);
        }
      }
#pragma unroll
      for (int o2 = 0; o2 < 16; ++o2) { pv0[o2] = waveRed(pv0[o2]); pv1[o2] = waveRed(pv1[o2]); }
      int w4 = tid >> 6;
      if ((tid & 63) == 0) {
#pragma unroll
        for (int o2 = 0; o2 < 16; ++o2) { red16[0][w4][o2] = pv0[o2]; red16[1][w4][o2] = pv1[o2]; }
      }
    }
    hold0 = hg0; hold1 = hg1;
    __syncthreads();                                           // B1

    // ================= Phase C =================
    // redundant g-sample per row
    int gidx0 = 0, gidx1 = 0;
    float lpg0, lpg1;
    {
      float lg[16];
#pragma unroll
      for (int n2 = 0; n2 < 16; ++n2)
        lg[n2] = red16[0][0][n2] + red16[0][1][n2] + red16[0][2][n2] + red16[0][3][n2] + bpi_sh[n2];
      float best = -3.402823466e+38f;
      for (int n2 = 0; n2 < 16; ++n2) {
        float v = lg[n2] + gg_sh[0][n2];
        if (v > best) { best = v; gidx0 = n2; }
      }
      float mx = lg[0];
      for (int n2 = 1; n2 < 16; ++n2) mx = fmaxf(mx, lg[n2]);
      float se = 0.f;
      for (int n2 = 0; n2 < 16; ++n2) se += expf(lg[n2] - mx);
      lpg0 = lg[gidx0] - mx - logf(se);
      float best1 = -3.402823466e+38f;
#pragma unroll
      for (int n2 = 0; n2 < 16; ++n2)
        lg[n2] = red16[1][0][n2] + red16[1][1][n2] + red16[1][2][n2] + red16[1][3][n2] + bpi_sh[n2];
      for (int n2 = 0; n2 < 16; ++n2) {
        float v = lg[n2] + gg_sh[1][n2];
        if (v > best1) { best1 = v; gidx1 = n2; }
      }
      float mx1 = lg[0];
      for (int n2 = 1; n2 < 16; ++n2) mx1 = fmaxf(mx1, lg[n2]);
      float se1 = 0.f;
      for (int n2 = 0; n2 < 16; ++n2) se1 += expf(lg[n2] - mx1);
      lpg1 = lg[gidx1] - mx1 - logf(se1);
    }
    // g' stored for next step (tid<32); uses same expression as inline below
    if (tid < 32) {
      g_sh[0][np][o] = c0 * M_sh[0][gidx0 * 32 + o] + omc0 * g_sh[0][pp][o];
      g_sh[1][np][o] = c1 * M_sh[1][gidx1 * 32 + o] + omc1 * g_sh[1][pp][o];
    }
    // redundant b-sample with inline g'
    float lpt0, lpt1;
    {
      float lb0 = bx_sh[0][0], lb1 = bx_sh[0][1];
      for (int s2 = 0; s2 < 32; ++s2) {
        float gv = c0 * M_sh[0][gidx0 * 32 + s2] + omc0 * g_sh[0][pp][s2];
        lb0 = fmaf(gv, wb_sh[0][s2], lb0);
        lb1 = fmaf(gv, wb_sh[1][s2], lb1);
      }
      int bidx = ((lb1 + bg_sh[0][1]) > (lb0 + bg_sh[0][0])) ? 1 : 0;
      float mb = fmaxf(lb0, lb1);
      float seb = expf(lb0 - mb) + expf(lb1 - mb);
      bnew0 = (float)bidx;
      lpt0 = lpg0 + ((bidx ? lb1 : lb0) - mb - logf(seb));
      float mb1_0 = bx_sh[1][0], mb1_1 = bx_sh[1][1];
      for (int s2 = 0; s2 < 32; ++s2) {
        float gv = c1 * M_sh[1][gidx1 * 32 + s2] + omc1 * g_sh[1][pp][s2];
        mb1_0 = fmaf(gv, wb_sh[0][s2], mb1_0);
        mb1_1 = fmaf(gv, wb_sh[1][s2], mb1_1);
      }
      int bidx1 = ((mb1_1 + bg_sh[1][1]) > (mb1_0 + bg_sh[1][0])) ? 1 : 0;
      float mbm = fmaxf(mb1_0, mb1_1);
      float seb1 = expf(mb1_0 - mbm) + expf(mb1_1 - mbm);
      bnew1 = (float)bidx1;
      lpt1 = lpg1 + ((bidx1 ? mb1_1 : mb1_0) - mbm - logf(seb1));
    }
    // next-step s with inline g' (r_sh[np] synced at B1); SH4[np] s-slots
    {
      const float* wfr = wf_sh + o * 65;
      sacc0 = c1n0;
#pragma unroll
      for (int j = 0; j < 32; ++j) sacc0 = fmaf(r_sh[0][np][j], wfr[j], sacc0);
#pragma unroll
      for (int j = 0; j < 32; ++j) {
        float gv = c0 * M_sh[0][gidx0 * 32 + j] + omc0 * g_sh[0][pp][j];
        sacc0 = fmaf(gv, wfr[32 + j], sacc0);
      }
      sacc0 = fmaf(bnew0, wfr[64], sacc0);
      ((float*)&SH4[np][0][o >> 1])[(o & 1) * 2] = sacc0;
      sacc1 = c1n1;
#pragma unroll
      for (int j = 0; j < 32; ++j) sacc1 = fmaf(r_sh[1][np][j], wfr[j], sacc1);
#pragma unroll
      for (int j = 0; j < 32; ++j) {
        float gv = c1 * M_sh[1][gidx1 * 32 + j] + omc1 * g_sh[1][pp][j];
        sacc1 = fmaf(gv, wfr[32 + j], sacc1);
      }
      sacc1 = fmaf(bnew1, wfr[64], sacc1);
      ((float*)&SH4[np][1][o >> 1])[(o & 1) * 2] = sacc1;
    }
    // red4 partials for next step
    {
      float pc0 = fmaf(wu_s, sacc0, wu_h * hold0);
      float q00 = ws0 * hold0, q01 = ws1 * hold0, q02 = ws2 * hold0;
      float pc1 = fmaf(wu_s, sacc1, wu_h * hold1);
      float q10 = ws0 * hold1, q11 = ws1 * hold1, q12 = ws2 * hold1;
      pc0 = waveRed(pc0); q00 = waveRed(q00); q01 = waveRed(q01); q02 = waveRed(q02);
      pc1 = waveRed(pc1); q10 = waveRed(q10); q11 = waveRed(q11); q12 = waveRed(q12);
      int w4 = tid >> 6;
      if ((tid & 63) == 0) {
        red4[0][w4][0] = pc0; red4[0][w4][1] = q00; red4[0][w4][2] = q01; red4[0][w4][3] = q02;
        red4[1][w4][0] = pc1; red4[1][w4][1] = q10; red4[1][w4][2] = q11; red4[1][w4][3] = q12;
      }
    }
    // outputs (h per-thread; smalls guarded; g inline-replicated)
    {
      size_t base0 = ((size_t)t * 256 + brow0) * TOT;
      size_t base1 = ((size_t)t * 256 + brow1) * TOT;
      out[base0 + 48 + o] = hg0;
      out[base1 + 48 + o] = hg1;
      if (tid < 16) {
        out[base0 + tid] = p_sh[0][np][tid];
        out[base1 + tid] = p_sh[1][np][tid];
      }
      if (tid < 32) {
        out[base0 + 16 + tid] = r_sh[0][np][tid];
        out[base1 + 16 + tid] = r_sh[1][np][tid];
        out[base0 + 304 + tid] = c0 * M_sh[0][gidx0 * 32 + tid] + omc0 * g_sh[0][pp][tid];
        out[base1 + 304 + tid] = c1 * M_sh[1][gidx1 * 32 + tid] + omc1 * g_sh[1][pp][tid];
      }
      if (tid == 32) { out[base0 + 336] = bnew0; out[base1 + 336] = bnew1; }
      if (tid == 33) { out[base0 + 337] = lpt0; out[base1 + 337] = lpt1; }
    }
    __syncthreads();                                           // B2
  }
}

// ------------------------------ host launch --------------------------------
extern "C" void kernel_launch(void* const* d_in, const int* in_sizes, int n_in,
                              void* d_out, int out_size, void* d_ws, size_t ws_size,
                              hipStream_t stream) {
  const float* obs    = (const float*)d_in[0];
  const float* task   = (const float*)d_in[1];
  const float* hx0    = (const float*)d_in[2];
  const float* W_ih   = (const float*)d_in[3];
  const float* W_hh   = (const float*)d_in[4];
  const float* b_ih   = (const float*)d_in[5];
  const float* b_hh   = (const float*)d_in[6];
  const float* W_f    = (const float*)d_in[7];
  const float* b_f    = (const float*)d_in[8];
  const float* W_u    = (const float*)d_in[9];
  const float* b_u    = (const float*)d_in[10];
  const float* W_s    = (const float*)d_in[11];
  const float* b_s    = (const float*)d_in[12];
  const float* W_pi   = (const float*)d_in[13];
  const float* b_pi   = (const float*)d_in[14];
  const float* W_beta = (const float*)d_in[15];
  const float* b_beta = (const float*)d_in[16];

  char* ws = (char*)d_ws;
  size_t off = 0;
  auto take = [&](size_t bytes) {
    size_t r = off;
    off += (bytes + 255) & ~(size_t)255;
    return r;
  };
  size_t off_WT4  = take((size_t)2 * 98304 * 16);
  size_t off_ggum = take((size_t)T_STEPS * B_ROWS * 16 * 4);
  size_t off_bgum = take((size_t)T_STEPS * B_ROWS * 2 * 4);
  size_t off_bx   = take((size_t)T_STEPS * B_ROWS * 2 * 4);
  size_t off_C1   = take((size_t)T_STEPS * B_ROWS * 256 * 4);
  if (off > ws_size) return;

  float* WT4  = (float*)(ws + off_WT4);
  float* ggum = (float*)(ws + off_ggum);
  float* bgum = (float*)(ws + off_bgum);
  float* bxv  = (float*)(ws + off_bx);
  float* C1   = (float*)(ws + off_C1);

  hipLaunchKernelGGL(prep4_k, dim3(256), dim3(768), 0, stream, W_ih, W_hh, (float4*)WT4);
  hipLaunchKernelGGL(rng_k, dim3(2304), dim3(256), 0, stream, ggum, bgum);
  hipLaunchKernelGGL(gemm1_k, dim3(2048), dim3(256), 0, stream, obs, W_f, b_f, C1);
  hipLaunchKernelGGL(bx_k, dim3(32768), dim3(256), 0, stream, obs, W_beta, b_beta, bxv);
  hipLaunchKernelGGL(seq_k, dim3(128), dim3(256), 0, stream,
                     hx0, task, W_f, WT4, b_ih, b_hh, W_u, b_u, W_s, b_s, W_pi, b_pi,
                     W_beta, C1, bxv, ggum, bgum, (float*)d_out);
}